// Round 9
// baseline (1373.625 us; speedup 1.0000x reference)
//
#include <hip/hip_runtime.h>

#define QLEN 256
#define DDIM 64
#define WOUT 32

typedef __bf16 b8v __attribute__((ext_vector_type(8)));
typedef float f4v __attribute__((ext_vector_type(4)));

__device__ __forceinline__ f4v MFMA(b8v a, b8v b, f4v c) {
  return __builtin_amdgcn_mfma_f32_16x16x32_bf16(a, b, c, 0, 0, 0);
}
__device__ __forceinline__ float sigmoidf_(float x) { return 1.0f/(1.0f+__expf(-x)); }
__device__ __forceinline__ float tanhf_(float x)    { return 1.0f - 2.0f/(__expf(2.0f*x)+1.0f); }

// ---------------- Kernel 1: Kalman scan (256 steps) ----------------
// 256 WGs x 512 threads (8 waves); WG owns 8 batch rows (M=16 tile, rows 8..15
// garbage-but-row-contained: A-rows only feed same-index C-rows, never read back).
// Conv: K-pair split (wave w & w+4 share col-tiles 2(w&3), 2(w&3)+1; each owns
// half of K) -> conv A-reads halve. Lanes lr>=8 read a shared zero row via
// pointer selects HOISTED once per phase (not per read) -> A-traffic halves again.
// Y phase overlaps 13 pre-feat conv chunks with the rot2 transcendental chain.
__global__ __launch_bounds__(512, 2)
void k_kalman(const float* __restrict__ x_in,
              const float* __restrict__ conv_w, const float* __restrict__ conv_b,
              const float* __restrict__ fc1_w,  const float* __restrict__ fc1_b,
              const float* __restrict__ fc2_w,  const float* __restrict__ fc2_b,
              const float* __restrict__ rot1_w, const float* __restrict__ rot1_b,
              const float* __restrict__ rot2_w, const float* __restrict__ rot2_b,
              float* __restrict__ out)
{
  __shared__ __align__(16) __bf16 SMB[12064];
  __shared__ __align__(16) float  SMF[3584];
  const int tid = threadIdx.x;
  const int w  = tid >> 6;      // wave 0..7
  const int l  = tid & 63;
  const int lr = l & 15;
  const int lg = l >> 4;
  const int wg = blockIdx.x;
  const bool lo  = (w < 4);
  const bool pr8 = (lr < 8);

  __bf16* XPB  = SMB;            // [8][72]   x_post bf16 (A for rot1)
  __bf16* T1   = SMB + 576;      // [8][136]  relu(rot1)
  __bf16* TC   = SMB + 1664;     // [8][136]  relu(conv)
  __bf16* T2   = SMB + 2752;     // [8][136]  relu(fc1)
  __bf16* FEAT = SMB + 3840;     // [5][8][200] feat ring (innov|xpv|diff)
  __bf16* ZROW = SMB + 11856;    // [208] zero row (never written after init)
  float*  XPF  = SMF;            // [8][64] x_post fp32 master
  float*  XPRI = SMF + 512;      // [8][64]
  float*  INV  = SMF + 1024;     // [8][64]
  float*  PART = SMF + 1536;     // [8 tiles][16 cols][16 rows] f32 conv partials

  for (int i = tid; i < 12064; i += 512) SMB[i] = (__bf16)0.0f;
  for (int i = tid; i < 3584;  i += 512) SMF[i] = 0.0f;

  const int hcol = 16*w + lr;          // N-split column for rot1/fc1/fc2
  const int t0   = 2*(w & 3);          // conv col-tile pair base

  // chunk c = L*6+q (L=lag, q=K-32-subtile). lo waves own q{0,1,2}, hi q{3,4,5}.
  // Y = pre-feat chunks (lags1-4 + lag0-xpv q2/q3); Z = lag0 innov/diff.
  constexpr int CH_LO[15] = {2, 6,7,8, 12,13,14, 18,19,20, 24,25,26, 0,1};
  constexpr int CH_HI[15] = {3, 9,10,11, 15,16,17, 21,22,23, 27,28,29, 4,5};

  // ---- register/AGPR-resident B fragments (weights, bf16) ----
  b8v r1B[2], f1B[4], f2B[4], cvB[15][2];
  #pragma unroll
  for (int q = 0; q < 2; ++q)
    #pragma unroll
    for (int j = 0; j < 8; ++j)
      r1B[q][j] = (__bf16)rot1_w[hcol*64 + q*32 + lg*8 + j];
  #pragma unroll
  for (int q = 0; q < 4; ++q)
    #pragma unroll
    for (int j = 0; j < 8; ++j)
      f1B[q][j] = (__bf16)fc1_w[hcol*128 + q*32 + lg*8 + j];
  {
    const int h2 = lo ? hcol : 0;   // fc2_w has 64 rows
    #pragma unroll
    for (int q = 0; q < 4; ++q)
      #pragma unroll
      for (int j = 0; j < 8; ++j)
        f2B[q][j] = (__bf16)fc2_w[h2*128 + q*32 + lg*8 + j];
  }
  #pragma unroll
  for (int i = 0; i < 15; ++i) {
    const int c = lo ? CH_LO[i] : CH_HI[i];
    const int L = c/6, q = c%6;
    #pragma unroll
    for (int ti = 0; ti < 2; ++ti)
      #pragma unroll
      for (int j = 0; j < 8; ++j)
        cvB[i][ti][j] =
          (__bf16)conv_w[((t0+ti)*16 + lr)*960 + (q*32 + lg*8 + j)*5 + (4-L)];
  }

  const float b_r1 = rot1_b[hcol];
  const float b_f1 = fc1_b[hcol];
  const float b_f2 = fc2_b[lo ? hcol : 0];
  const float bc0  = conv_b[t0*16 + lr];
  const float bc1  = conv_b[(t0+1)*16 + lr];
  const float r2w00 = rot2_w[l],       r2w01 = rot2_w[64 + l];
  const float r2w10 = rot2_w[128 + l], r2w11 = rot2_w[192 + l];
  const float rb0 = rot2_b[0], rb1 = rot2_b[1];
  const float PI_F = 3.14159274f;

  // hoisted masked A-base pointers (select once, not per read)
  const __bf16* zb    = ZROW + lg*8;
  const __bf16* xpb_p = pr8 ? (XPB + lr*72  + lg*8) : zb;
  const __bf16* tc_p  = pr8 ? (TC  + lr*136 + lg*8) : zb;
  const __bf16* t2_p  = pr8 ? (T2  + lr*136 + lg*8) : zb;
  const __bf16* featb = FEAT + lr*200 + lg*8;   // + s5*1600 per step

  const float* xptr = x_in + ((long)(wg*8 + w)*QLEN)*DDIM + l;
  float y_cur = xptr[0];
  float y_prv = y_cur;
  int slot = 0;

  __syncthreads();

  for (int t = 0; t < QLEN; ++t) {
    // ---- R: t1 = relu(x_post @ rot1_w^T + b), col-tile w ----
    {
      b8v a0 = *(const b8v*)(xpb_p);
      b8v a1 = *(const b8v*)(xpb_p + 32);
      f4v C = {};
      C = MFMA(a0, r1B[0], C);
      C = MFMA(a1, r1B[1], C);
      if (lg < 2) {
        #pragma unroll
        for (int r = 0; r < 4; ++r) {
          float v = C[r] + b_r1; v = v > 0.f ? v : 0.f;
          T1[(lg*4+r)*136 + hcol] = (__bf16)v;
        }
      }
    }
    __syncthreads();   // B1: T1 ready

    // ---- Y: 13 pre-feat conv chunks (3 accums/tile) || rot2 + rotation + feat ----
    float y_nxt = (t+1 < QLEN) ? xptr[(t+1)*DDIM] : y_cur;
    // per-step masked feat lag pointers (5 selects)
    const __bf16* fbp[5];
    #pragma unroll
    for (int L = 0; L < 5; ++L) {
      int s5 = slot - L; if (s5 < 0) s5 += 5;
      fbp[L] = pr8 ? (featb + s5*1600) : zb;
    }
    f4v P0 = {}, P1 = {}, P2 = {}, Q0 = {}, Q1 = {}, Q2 = {};
    {
      #pragma unroll
      for (int i = 0; i < 13; ++i) {
        const int c = lo ? CH_LO[i] : CH_HI[i];
        const int L = c/6, q = c%6;
        b8v a = *(const b8v*)&fbp[L][q*32];
        const int s3 = i % 3;
        if      (s3 == 0) { P0 = MFMA(a, cvB[i][0], P0); Q0 = MFMA(a, cvB[i][1], Q0); }
        else if (s3 == 1) { P1 = MFMA(a, cvB[i][0], P1); Q1 = MFMA(a, cvB[i][1], Q1); }
        else              { P2 = MFMA(a, cvB[i][0], P2); Q2 = MFMA(a, cvB[i][1], Q2); }
      }
    }
    {
      float t1a = (float)T1[w*136 + l];
      float t1b = (float)T1[w*136 + 64 + l];
      float acc0 = t1a*r2w00 + t1b*r2w01;
      float acc1 = t1a*r2w10 + t1b*r2w11;
      #pragma unroll
      for (int m = 1; m < 64; m <<= 1) {
        acc0 += __shfl_xor(acc0, m, 64);
        acc1 += __shfl_xor(acc1, m, 64);
      }
      float rho = 1.5f * sigmoidf_(acc0 + rb0);
      float phi = PI_F * tanhf_(acc1 + rb1);
      float cc = rho * __cosf(phi);
      float ss = rho * __sinf(phi);
      float lo32 = XPF[w*64 + (l & 31)];
      float hi32 = XPF[w*64 + (l & 31) + 32];
      float xpri = (l < 32) ? (lo32*cc - hi32*ss) : (lo32*ss + hi32*cc);
      float innov = y_cur - xpri;
      float diff  = y_cur - y_prv;
      __bf16* fr = FEAT + slot*1600 + w*200;
      fr[l]       = (__bf16)innov;
      fr[128 + l] = (__bf16)diff;     // xpv slice [64+l] prewritten by prev F2
      XPRI[w*64 + l] = xpri;
      INV [w*64 + l] = innov;
    }
    __syncthreads();   // B2: feat(t) ready

    // ---- Z: 2 post-feat lag0 chunks; hi publishes partials ----
    {
      const __bf16* fb0 = pr8 ? (featb + slot*1600) : zb;
      #pragma unroll
      for (int i = 13; i < 15; ++i) {
        const int q = (lo ? CH_LO[i] : CH_HI[i]) % 6;
        b8v a = *(const b8v*)&fb0[q*32];
        if (i == 13) { P0 = MFMA(a, cvB[i][0], P0); Q0 = MFMA(a, cvB[i][1], Q0); }
        else         { P1 = MFMA(a, cvB[i][0], P1); Q1 = MFMA(a, cvB[i][1], Q1); }
      }
      if (!lo) {
        f4v s0, s1;
        #pragma unroll
        for (int r = 0; r < 4; ++r) { s0[r] = P0[r]+P1[r]+P2[r]; s1[r] = Q0[r]+Q1[r]+Q2[r]; }
        *(f4v*)&PART[(t0*16 + lr)*16 + lg*4]     = s0;
        *(f4v*)&PART[((t0+1)*16 + lr)*16 + lg*4] = s1;
      }
    }
    __syncthreads();   // B3: partials ready

    // ---- C: combine + bias + relu -> TC (lo waves) ----
    if (lo) {
      f4v p0 = *(const f4v*)&PART[(t0*16 + lr)*16 + lg*4];
      f4v p1 = *(const f4v*)&PART[((t0+1)*16 + lr)*16 + lg*4];
      if (lg < 2) {
        #pragma unroll
        for (int r = 0; r < 4; ++r) {
          float v0 = P0[r]+P1[r]+P2[r] + p0[r] + bc0; v0 = v0 > 0.f ? v0 : 0.f;
          float v1 = Q0[r]+Q1[r]+Q2[r] + p1[r] + bc1; v1 = v1 > 0.f ? v1 : 0.f;
          TC[(lg*4+r)*136 + t0*16 + lr]     = (__bf16)v0;
          TC[(lg*4+r)*136 + (t0+1)*16 + lr] = (__bf16)v1;
        }
      }
    }
    __syncthreads();   // B4: TC ready

    // ---- F1: fc1 col-tile w ----
    {
      f4v D0 = {}, D1 = {};
      #pragma unroll
      for (int q = 0; q < 4; ++q) {
        b8v a = *(const b8v*)(tc_p + q*32);
        if (q & 1) D1 = MFMA(a, f1B[q], D1); else D0 = MFMA(a, f1B[q], D0);
      }
      if (lg < 2) {
        #pragma unroll
        for (int r = 0; r < 4; ++r) {
          float v = D0[r] + D1[r] + b_f1; v = v > 0.f ? v : 0.f;
          T2[(lg*4+r)*136 + hcol] = (__bf16)v;
        }
      }
    }
    __syncthreads();   // B5: T2 ready

    const int slot_next = (slot == 4) ? 0 : slot + 1;
    // ---- F2: K = sigmoid(fc2), x_post update + next-step xpv prewrite (waves 0..3) ----
    if (lo) {
      f4v D0 = {}, D1 = {};
      #pragma unroll
      for (int q = 0; q < 4; ++q) {
        b8v a = *(const b8v*)(t2_p + q*32);
        if (q & 1) D1 = MFMA(a, f2B[q], D1); else D0 = MFMA(a, f2B[q], D0);
      }
      if (lg < 2) {
        #pragma unroll
        for (int r = 0; r < 4; ++r) {
          int e = lg*4 + r;
          float K = sigmoidf_(D0[r] + D1[r] + b_f2);
          float xn = XPRI[e*64 + hcol] + K * INV[e*64 + hcol];
          XPF[e*64 + hcol] = xn;
          XPB[e*72 + hcol] = (__bf16)xn;
          FEAT[slot_next*1600 + e*200 + 64 + hcol] = (__bf16)xn;  // xpv of feat(t+1)
        }
      }
    }
    __syncthreads();   // B6: x_post ready

    y_prv = y_cur; y_cur = y_nxt;
    slot = slot_next;
  }

  // stash fp32 x_post into out[b][0][:] (GRU kernel reads then overwrites)
  out[((long)(wg*8 + w)*WOUT)*DDIM + l] = XPF[w*64 + l];
}

// ---------------- Kernel 2: GRU head (32 steps) ----------------
// 256 WGs x 512 threads; each WG owns 8 batch rows (M=16 tile, rows 8..15 isolated).
__global__ __launch_bounds__(512, 2)
void k_gru(const float* __restrict__ gru_wih, const float* __restrict__ gru_whh,
           const float* __restrict__ gru_bih, const float* __restrict__ gru_bhh,
           const float* __restrict__ out_w,   const float* __restrict__ out_b,
           float* __restrict__ out)
{
  __shared__ __align__(16) __bf16 CUR[16*72];
  __shared__ __align__(16) __bf16 HB [16*136];
  const int tid = threadIdx.x;
  const int w  = tid >> 6, l = tid & 63, lr = l & 15, lg = l >> 4;
  const int g = blockIdx.x;

  for (int i = tid; i < 16*136; i += 512) HB[i] = (__bf16)0.f;
  for (int i = tid; i < 16*72; i += 512) CUR[i] = (__bf16)0.f;
  __syncthreads();
  for (int i = tid; i < 8*64; i += 512) {
    int e = i >> 6, d = i & 63;
    CUR[e*72 + d] = (__bf16)out[((long)(g*8 + e)*WOUT)*DDIM + d];
  }

  b8v fih[3][2], fhh[3][4], fo[4];
  #pragma unroll
  for (int n3 = 0; n3 < 3; ++n3) {
    int row = 16*(w + 8*n3) + lr;
    #pragma unroll
    for (int q = 0; q < 2; ++q)
      #pragma unroll
      for (int j = 0; j < 8; ++j)
        fih[n3][q][j] = (__bf16)gru_wih[row*64 + q*32 + lg*8 + j];
    #pragma unroll
    for (int q = 0; q < 4; ++q)
      #pragma unroll
      for (int j = 0; j < 8; ++j)
        fhh[n3][q][j] = (__bf16)gru_whh[row*128 + q*32 + lg*8 + j];
  }
  {
    int row = 16*(w & 3) + lr;
    #pragma unroll
    for (int q = 0; q < 4; ++q)
      #pragma unroll
      for (int j = 0; j < 8; ++j)
        fo[q][j] = (__bf16)out_w[row*128 + q*32 + lg*8 + j];
  }
  const int jh = 16*w + lr;
  const float b_ir = gru_bih[jh], b_iz = gru_bih[128+jh], b_in = gru_bih[256+jh];
  const float b_hr = gru_bhh[jh], b_hz = gru_bhh[128+jh], b_hn = gru_bhh[256+jh];
  const float b_o  = out_b[16*(w & 3) + lr];
  const int dcol = 16*(w & 3) + lr;
  __syncthreads();

  for (int s = 0; s < WOUT; ++s) {
    f4v cI[3] = {}, cH[3] = {};
    #pragma unroll
    for (int q = 0; q < 2; ++q) {
      b8v a = *(const b8v*)&CUR[lr*72 + q*32 + lg*8];
      #pragma unroll
      for (int n3 = 0; n3 < 3; ++n3) cI[n3] = MFMA(a, fih[n3][q], cI[n3]);
    }
    #pragma unroll
    for (int q = 0; q < 4; ++q) {
      b8v a = *(const b8v*)&HB[lr*136 + q*32 + lg*8];
      #pragma unroll
      for (int n3 = 0; n3 < 3; ++n3) cH[n3] = MFMA(a, fhh[n3][q], cH[n3]);
    }
    __syncthreads();

    #pragma unroll
    for (int r = 0; r < 4; ++r) {
      int e = lg*4 + r;
      float ir = cI[0][r] + b_ir, iz = cI[1][r] + b_iz, in_ = cI[2][r] + b_in;
      float hr = cH[0][r] + b_hr, hz = cH[1][r] + b_hz, hn  = cH[2][r] + b_hn;
      float rr = sigmoidf_(ir + hr);
      float zz = sigmoidf_(iz + hz);
      float nn = tanhf_(in_ + rr*hn);
      float hold = (float)HB[e*136 + jh];
      float hnew = (1.f - zz)*nn + zz*hold;
      HB[e*136 + jh] = (__bf16)hnew;
    }
    __syncthreads();

    if (w < 4) {
      f4v C0 = {};
      #pragma unroll
      for (int q = 0; q < 4; ++q) {
        b8v a = *(const b8v*)&HB[lr*136 + q*32 + lg*8];
        C0 = MFMA(a, fo[q], C0);
      }
      #pragma unroll
      for (int r = 0; r < 4; ++r) {
        int e = lg*4 + r;
        float cn = (float)CUR[e*72 + dcol] + C0[r] + b_o;
        CUR[e*72 + dcol] = (__bf16)cn;
        if (e < 8)
          out[(((long)(g*8 + e))*WOUT + s)*DDIM + dcol] = cn;
      }
    }
    __syncthreads();
  }
}

extern "C" void kernel_launch(void* const* d_in, const int* in_sizes, int n_in,
                              void* d_out, int out_size, void* d_ws, size_t ws_size,
                              hipStream_t stream) {
  (void)in_sizes; (void)n_in; (void)d_ws; (void)ws_size; (void)out_size;
  const float* x_in   = (const float*)d_in[0];
  const float* conv_w = (const float*)d_in[2];
  const float* conv_b = (const float*)d_in[3];
  const float* fc1_w  = (const float*)d_in[4];
  const float* fc1_b  = (const float*)d_in[5];
  const float* fc2_w  = (const float*)d_in[6];
  const float* fc2_b  = (const float*)d_in[7];
  const float* rot1_w = (const float*)d_in[8];
  const float* rot1_b = (const float*)d_in[9];
  const float* rot2_w = (const float*)d_in[10];
  const float* rot2_b = (const float*)d_in[11];
  const float* gwih   = (const float*)d_in[12];
  const float* gwhh   = (const float*)d_in[13];
  const float* gbih   = (const float*)d_in[14];
  const float* gbhh   = (const float*)d_in[15];
  const float* ow     = (const float*)d_in[16];
  const float* ob     = (const float*)d_in[17];
  float* out = (float*)d_out;

  k_kalman<<<256, 512, 0, stream>>>(x_in, conv_w, conv_b, fc1_w, fc1_b,
                                    fc2_w, fc2_b, rot1_w, rot1_b,
                                    rot2_w, rot2_b, out);
  k_gru<<<256, 512, 0, stream>>>(gwih, gwhh, gbih, gbhh, ow, ob, out);
}

// Round 10
// 803.717 us; speedup vs baseline: 1.7091x; 1.7091x over previous
//
#include <hip/hip_runtime.h>

#define QLEN 256
#define DDIM 64
#define WOUT 32

typedef __bf16 b8v __attribute__((ext_vector_type(8)));
typedef float f4v __attribute__((ext_vector_type(4)));

__device__ __forceinline__ f4v MFMA(b8v a, b8v b, f4v c) {
  return __builtin_amdgcn_mfma_f32_16x16x32_bf16(a, b, c, 0, 0, 0);
}
__device__ __forceinline__ float sigmoidf_(float x) { return 1.0f/(1.0f+__expf(-x)); }
__device__ __forceinline__ float tanhf_(float x)    { return 1.0f - 2.0f/(__expf(2.0f*x)+1.0f); }

// ---------------- Kernel 1: Kalman scan (256 steps) ----------------
// 256 WGs x 512 threads (8 waves); WG owns 8 batch rows (M=16 tile, rows 8..15
// garbage-but-row-contained). N-split: wave w owns cols 16w..16w+15 of every GEMM.
// This round: (1) T1 never materialized — rot2 partials computed in-register from
// the rot1 C-fragment (16-lane butterfly) into PR[16][16]f32; (2) conv lags1-4 of
// step t+1 issue during phases C/D/E of step t (U/V accumulator double-buffer),
// so no phase carries more than 10 conv MFMAs and phase A is 4 MFMAs + butterfly.
__global__ __launch_bounds__(512, 2)
void k_kalman(const float* __restrict__ x_in,
              const float* __restrict__ conv_w, const float* __restrict__ conv_b,
              const float* __restrict__ fc1_w,  const float* __restrict__ fc1_b,
              const float* __restrict__ fc2_w,  const float* __restrict__ fc2_b,
              const float* __restrict__ rot1_w, const float* __restrict__ rot1_b,
              const float* __restrict__ rot2_w, const float* __restrict__ rot2_b,
              float* __restrict__ out)
{
  __shared__ __align__(16) __bf16 SMB[12352];  // incl. overhang slack for garbage-row reads
  __shared__ __align__(16) float  SMF[1792];
  const int tid = threadIdx.x;
  const int w  = tid >> 6;      // wave 0..7
  const int l  = tid & 63;
  const int lr = l & 15;
  const int lg = l >> 4;
  const int wg = blockIdx.x;

  __bf16* XPB  = SMB;            // [8][72]   x_post bf16 (A for rot1)
  __bf16* TC   = SMB + 576;      // [8][136]  relu(conv)
  __bf16* T2   = SMB + 1664;     // [8][136]  relu(fc1)
  __bf16* FEAT = SMB + 2752;     // [5][8][200] feat ring (innov|xpv|diff)
  float*  XPF  = SMF;            // [8][64] x_post fp32 master
  float*  XPRI = SMF + 512;      // [8][64]
  float*  INV  = SMF + 1024;     // [8][64]
  float*  PR   = SMF + 1536;     // [16][16] rot2 partials: [row][w'*2+o]

  for (int i = tid; i < 12352; i += 512) SMB[i] = (__bf16)0.0f;
  for (int i = tid; i < 1792;  i += 512) SMF[i] = 0.0f;

  const int hcol = 16*w + lr;    // this wave's output column in every GEMM

  // ---- register/AGPR-resident B fragments (weights, bf16) ----
  b8v r1B[2], f1B[4], f2B[4], cvB[30];
  #pragma unroll
  for (int q = 0; q < 2; ++q)
    #pragma unroll
    for (int j = 0; j < 8; ++j)
      r1B[q][j] = (__bf16)rot1_w[hcol*64 + q*32 + lg*8 + j];
  #pragma unroll
  for (int q = 0; q < 4; ++q)
    #pragma unroll
    for (int j = 0; j < 8; ++j)
      f1B[q][j] = (__bf16)fc1_w[hcol*128 + q*32 + lg*8 + j];
  {
    const int h2 = (w < 4) ? hcol : 0;   // fc2_w has 64 rows
    #pragma unroll
    for (int q = 0; q < 4; ++q)
      #pragma unroll
      for (int j = 0; j < 8; ++j)
        f2B[q][j] = (__bf16)fc2_w[h2*128 + q*32 + lg*8 + j];
  }
  #pragma unroll
  for (int c = 0; c < 30; ++c) {
    const int L = c/6, q = c%6;
    #pragma unroll
    for (int j = 0; j < 8; ++j)
      cvB[c][j] = (__bf16)conv_w[hcol*960 + (q*32 + lg*8 + j)*5 + (4-L)];
  }

  const float b_r1 = rot1_b[hcol];
  const float b_f1 = fc1_b[hcol];
  const float b_f2 = fc2_b[(w < 4) ? hcol : 0];
  const float bc   = conv_b[hcol];
  const float w2c0 = rot2_w[hcol];         // rot2 col weights for this lane's col
  const float w2c1 = rot2_w[128 + hcol];
  const float rb0 = rot2_b[0], rb1 = rot2_b[1];
  const float PI_F = 3.14159274f;

  const float* xptr = x_in + ((long)(wg*8 + w)*QLEN)*DDIM + l;
  float y_cur = xptr[0];
  float y_prv = y_cur;
  int slot = 0;

  // conv accumulators: U = step t (consumed in C), V = step t+1 (built in C/D/E)
  f4v U0 = {}, U1 = {}, U2 = {}, V0 = {}, V1 = {}, V2 = {};

  __syncthreads();

  for (int t = 0; t < QLEN; ++t) {
    int m1 = slot - 1; if (m1 < 0) m1 += 5;   // feat(t-1)
    int m2 = slot - 2; if (m2 < 0) m2 += 5;   // feat(t-2)
    int m3 = slot - 3; if (m3 < 0) m3 += 5;   // feat(t-3)
    const int slot_next = (slot == 4) ? 0 : slot + 1;

    // ---- A: rot1 + conv lag0-xpv (q2,q3) + in-register rot2 partials ----
    {
      const __bf16* fx = FEAT + slot*1600 + lr*200 + lg*8;
      b8v ax2 = *(const b8v*)&fx[2*32];
      b8v ax3 = *(const b8v*)&fx[3*32];
      U0 = MFMA(ax2, cvB[2], U0);
      U1 = MFMA(ax3, cvB[3], U1);
      b8v a0 = *(const b8v*)&XPB[lr*72      + lg*8];
      b8v a1 = *(const b8v*)&XPB[lr*72 + 32 + lg*8];
      f4v C = {};
      C = MFMA(a0, r1B[0], C);
      C = MFMA(a1, r1B[1], C);
      float p0[4], p1[4];
      #pragma unroll
      for (int r = 0; r < 4; ++r) {
        float v = C[r] + b_r1; v = v > 0.f ? v : 0.f;   // t1 value, col hcol, row lg*4+r
        p0[r] = v * w2c0;
        p1[r] = v * w2c1;
      }
      #pragma unroll
      for (int m = 1; m < 16; m <<= 1) {
        #pragma unroll
        for (int r = 0; r < 4; ++r) {
          p0[r] += __shfl_xor(p0[r], m, 64);
          p1[r] += __shfl_xor(p1[r], m, 64);
        }
      }
      if (lr == 0) {
        #pragma unroll
        for (int r = 0; r < 4; ++r) {
          PR[(lg*4+r)*16 + 2*w]     = p0[r];
          PR[(lg*4+r)*16 + 2*w + 1] = p1[r];
        }
      }
    }
    __syncthreads();   // B1: PR ready

    // ---- B: rot2 sum + transcendentals + rotation + feat(t) writes ----
    float y_nxt = (t+1 < QLEN) ? xptr[(t+1)*DDIM] : y_cur;
    {
      f4v s = *(const f4v*)&PR[w*16];
      s += *(const f4v*)&PR[w*16 + 4];
      s += *(const f4v*)&PR[w*16 + 8];
      s += *(const f4v*)&PR[w*16 + 12];
      float rho = 1.5f * sigmoidf_(s[0] + s[2] + rb0);
      float phi = PI_F * tanhf_(s[1] + s[3] + rb1);
      float cc = rho * __cosf(phi);
      float ss = rho * __sinf(phi);
      float lo32 = XPF[w*64 + (l & 31)];
      float hi32 = XPF[w*64 + (l & 31) + 32];
      float xpri = (l < 32) ? (lo32*cc - hi32*ss) : (lo32*ss + hi32*cc);
      float innov = y_cur - xpri;
      float diff  = y_cur - y_prv;
      __bf16* fr = FEAT + slot*1600 + w*200;
      fr[l]       = (__bf16)innov;
      fr[128 + l] = (__bf16)diff;     // xpv slice [64..127] prewritten by prev E
      XPRI[w*64 + l] = xpri;
      INV [w*64 + l] = innov;
    }
    __syncthreads();   // B2: feat(t) complete

    // ---- C: conv lag0 innov/diff (U) + lag1(t+1) (V, same A-loads) + TC ----
    {
      const __bf16* f0 = FEAT + slot*1600 + lr*200 + lg*8;
      b8v aq0 = *(const b8v*)&f0[0*32];
      b8v aq1 = *(const b8v*)&f0[1*32];
      b8v aq2 = *(const b8v*)&f0[2*32];
      b8v aq3 = *(const b8v*)&f0[3*32];
      b8v aq4 = *(const b8v*)&f0[4*32];
      b8v aq5 = *(const b8v*)&f0[5*32];
      U2 = MFMA(aq0, cvB[0], U2);
      U0 = MFMA(aq1, cvB[1], U0);
      U1 = MFMA(aq4, cvB[4], U1);
      U2 = MFMA(aq5, cvB[5], U2);
      V0 = MFMA(aq0, cvB[6],  V0);
      V1 = MFMA(aq1, cvB[7],  V1);
      V2 = MFMA(aq2, cvB[8],  V2);
      V0 = MFMA(aq3, cvB[9],  V0);
      V1 = MFMA(aq4, cvB[10], V1);
      V2 = MFMA(aq5, cvB[11], V2);
      if (lg < 2) {
        #pragma unroll
        for (int r = 0; r < 4; ++r) {
          float v = U0[r] + U1[r] + U2[r] + bc; v = v > 0.f ? v : 0.f;
          TC[(lg*4+r)*136 + hcol] = (__bf16)v;
        }
      }
    }
    __syncthreads();   // B3: TC ready

    // ---- D: fc1 + conv lags2-3 of t+1 (V) ----
    {
      f4v D0 = {}, D1 = {};
      const __bf16* tcp = TC + lr*136 + lg*8;
      #pragma unroll
      for (int q = 0; q < 4; ++q) {
        b8v a = *(const b8v*)&tcp[q*32];
        if (q & 1) D1 = MFMA(a, f1B[q], D1); else D0 = MFMA(a, f1B[q], D0);
      }
      const __bf16* fl2 = FEAT + m1*1600 + lr*200 + lg*8;
      const __bf16* fl3 = FEAT + m2*1600 + lr*200 + lg*8;
      {
        b8v a;
        a = *(const b8v*)&fl2[0*32];  V0 = MFMA(a, cvB[12], V0);
        a = *(const b8v*)&fl2[1*32];  V1 = MFMA(a, cvB[13], V1);
        a = *(const b8v*)&fl2[2*32];  V2 = MFMA(a, cvB[14], V2);
        a = *(const b8v*)&fl2[3*32];  V0 = MFMA(a, cvB[15], V0);
        a = *(const b8v*)&fl2[4*32];  V1 = MFMA(a, cvB[16], V1);
        a = *(const b8v*)&fl2[5*32];  V2 = MFMA(a, cvB[17], V2);
        a = *(const b8v*)&fl3[0*32];  V0 = MFMA(a, cvB[18], V0);
        a = *(const b8v*)&fl3[1*32];  V1 = MFMA(a, cvB[19], V1);
        a = *(const b8v*)&fl3[2*32];  V2 = MFMA(a, cvB[20], V2);
        a = *(const b8v*)&fl3[3*32];  V0 = MFMA(a, cvB[21], V0);
        a = *(const b8v*)&fl3[4*32];  V1 = MFMA(a, cvB[22], V1);
        a = *(const b8v*)&fl3[5*32];  V2 = MFMA(a, cvB[23], V2);
      }
      if (lg < 2) {
        #pragma unroll
        for (int r = 0; r < 4; ++r) {
          float v = D0[r] + D1[r] + b_f1; v = v > 0.f ? v : 0.f;
          T2[(lg*4+r)*136 + hcol] = (__bf16)v;
        }
      }
    }
    __syncthreads();   // B4: T2 ready

    // ---- E: fc2 (waves 0-3) + conv lag4 of t+1 (V, all waves) + x_post ----
    {
      const __bf16* fl4 = FEAT + m3*1600 + lr*200 + lg*8;
      b8v a;
      a = *(const b8v*)&fl4[0*32];  V0 = MFMA(a, cvB[24], V0);
      a = *(const b8v*)&fl4[1*32];  V1 = MFMA(a, cvB[25], V1);
      a = *(const b8v*)&fl4[2*32];  V2 = MFMA(a, cvB[26], V2);
      a = *(const b8v*)&fl4[3*32];  V0 = MFMA(a, cvB[27], V0);
      a = *(const b8v*)&fl4[4*32];  V1 = MFMA(a, cvB[28], V1);
      a = *(const b8v*)&fl4[5*32];  V2 = MFMA(a, cvB[29], V2);
      if (w < 4) {
        f4v D0 = {}, D1 = {};
        const __bf16* t2p = T2 + lr*136 + lg*8;
        #pragma unroll
        for (int q = 0; q < 4; ++q) {
          b8v b = *(const b8v*)&t2p[q*32];
          if (q & 1) D1 = MFMA(b, f2B[q], D1); else D0 = MFMA(b, f2B[q], D0);
        }
        if (lg < 2) {
          #pragma unroll
          for (int r = 0; r < 4; ++r) {
            int e = lg*4 + r;
            float K = sigmoidf_(D0[r] + D1[r] + b_f2);
            float xn = XPRI[e*64 + hcol] + K * INV[e*64 + hcol];
            XPF[e*64 + hcol] = xn;
            XPB[e*72 + hcol] = (__bf16)xn;
            FEAT[slot_next*1600 + e*200 + 64 + hcol] = (__bf16)xn;  // xpv of feat(t+1)
          }
        }
      }
    }
    __syncthreads();   // B5: x_post + xpv(t+1) ready

    // handoff: V (t+1 partials) becomes U; V cleared
    U0 = V0; U1 = V1; U2 = V2;
    V0 = (f4v){}; V1 = (f4v){}; V2 = (f4v){};

    y_prv = y_cur; y_cur = y_nxt;
    slot = slot_next;
  }

  // stash fp32 x_post into out[b][0][:] (GRU kernel reads then overwrites)
  out[((long)(wg*8 + w)*WOUT)*DDIM + l] = XPF[w*64 + l];
}

// ---------------- Kernel 2: GRU head (32 steps) ----------------
// 256 WGs x 512 threads; each WG owns 8 batch rows (M=16 tile, rows 8..15 isolated).
__global__ __launch_bounds__(512, 2)
void k_gru(const float* __restrict__ gru_wih, const float* __restrict__ gru_whh,
           const float* __restrict__ gru_bih, const float* __restrict__ gru_bhh,
           const float* __restrict__ out_w,   const float* __restrict__ out_b,
           float* __restrict__ out)
{
  __shared__ __align__(16) __bf16 CUR[16*72];
  __shared__ __align__(16) __bf16 HB [16*136];
  const int tid = threadIdx.x;
  const int w  = tid >> 6, l = tid & 63, lr = l & 15, lg = l >> 4;
  const int g = blockIdx.x;

  for (int i = tid; i < 16*136; i += 512) HB[i] = (__bf16)0.f;
  for (int i = tid; i < 16*72; i += 512) CUR[i] = (__bf16)0.f;
  __syncthreads();
  for (int i = tid; i < 8*64; i += 512) {
    int e = i >> 6, d = i & 63;
    CUR[e*72 + d] = (__bf16)out[((long)(g*8 + e)*WOUT)*DDIM + d];
  }

  b8v fih[3][2], fhh[3][4], fo[4];
  #pragma unroll
  for (int n3 = 0; n3 < 3; ++n3) {
    int row = 16*(w + 8*n3) + lr;
    #pragma unroll
    for (int q = 0; q < 2; ++q)
      #pragma unroll
      for (int j = 0; j < 8; ++j)
        fih[n3][q][j] = (__bf16)gru_wih[row*64 + q*32 + lg*8 + j];
    #pragma unroll
    for (int q = 0; q < 4; ++q)
      #pragma unroll
      for (int j = 0; j < 8; ++j)
        fhh[n3][q][j] = (__bf16)gru_whh[row*128 + q*32 + lg*8 + j];
  }
  {
    int row = 16*(w & 3) + lr;
    #pragma unroll
    for (int q = 0; q < 4; ++q)
      #pragma unroll
      for (int j = 0; j < 8; ++j)
        fo[q][j] = (__bf16)out_w[row*128 + q*32 + lg*8 + j];
  }
  const int jh = 16*w + lr;
  const float b_ir = gru_bih[jh], b_iz = gru_bih[128+jh], b_in = gru_bih[256+jh];
  const float b_hr = gru_bhh[jh], b_hz = gru_bhh[128+jh], b_hn = gru_bhh[256+jh];
  const float b_o  = out_b[16*(w & 3) + lr];
  const int dcol = 16*(w & 3) + lr;
  __syncthreads();

  for (int s = 0; s < WOUT; ++s) {
    f4v cI[3] = {}, cH[3] = {};
    #pragma unroll
    for (int q = 0; q < 2; ++q) {
      b8v a = *(const b8v*)&CUR[lr*72 + q*32 + lg*8];
      #pragma unroll
      for (int n3 = 0; n3 < 3; ++n3) cI[n3] = MFMA(a, fih[n3][q], cI[n3]);
    }
    #pragma unroll
    for (int q = 0; q < 4; ++q) {
      b8v a = *(const b8v*)&HB[lr*136 + q*32 + lg*8];
      #pragma unroll
      for (int n3 = 0; n3 < 3; ++n3) cH[n3] = MFMA(a, fhh[n3][q], cH[n3]);
    }
    __syncthreads();

    #pragma unroll
    for (int r = 0; r < 4; ++r) {
      int e = lg*4 + r;
      float ir = cI[0][r] + b_ir, iz = cI[1][r] + b_iz, in_ = cI[2][r] + b_in;
      float hr = cH[0][r] + b_hr, hz = cH[1][r] + b_hz, hn  = cH[2][r] + b_hn;
      float rr = sigmoidf_(ir + hr);
      float zz = sigmoidf_(iz + hz);
      float nn = tanhf_(in_ + rr*hn);
      float hold = (float)HB[e*136 + jh];
      float hnew = (1.f - zz)*nn + zz*hold;
      HB[e*136 + jh] = (__bf16)hnew;
    }
    __syncthreads();

    if (w < 4) {
      f4v C0 = {};
      #pragma unroll
      for (int q = 0; q < 4; ++q) {
        b8v a = *(const b8v*)&HB[lr*136 + q*32 + lg*8];
        C0 = MFMA(a, fo[q], C0);
      }
      #pragma unroll
      for (int r = 0; r < 4; ++r) {
        int e = lg*4 + r;
        float cn = (float)CUR[e*72 + dcol] + C0[r] + b_o;
        CUR[e*72 + dcol] = (__bf16)cn;
        if (e < 8)
          out[(((long)(g*8 + e))*WOUT + s)*DDIM + dcol] = cn;
      }
    }
    __syncthreads();
  }
}

extern "C" void kernel_launch(void* const* d_in, const int* in_sizes, int n_in,
                              void* d_out, int out_size, void* d_ws, size_t ws_size,
                              hipStream_t stream) {
  (void)in_sizes; (void)n_in; (void)d_ws; (void)ws_size; (void)out_size;
  const float* x_in   = (const float*)d_in[0];
  const float* conv_w = (const float*)d_in[2];
  const float* conv_b = (const float*)d_in[3];
  const float* fc1_w  = (const float*)d_in[4];
  const float* fc1_b  = (const float*)d_in[5];
  const float* fc2_w  = (const float*)d_in[6];
  const float* fc2_b  = (const float*)d_in[7];
  const float* rot1_w = (const float*)d_in[8];
  const float* rot1_b = (const float*)d_in[9];
  const float* rot2_w = (const float*)d_in[10];
  const float* rot2_b = (const float*)d_in[11];
  const float* gwih   = (const float*)d_in[12];
  const float* gwhh   = (const float*)d_in[13];
  const float* gbih   = (const float*)d_in[14];
  const float* gbhh   = (const float*)d_in[15];
  const float* ow     = (const float*)d_in[16];
  const float* ob     = (const float*)d_in[17];
  float* out = (float*)d_out;

  k_kalman<<<256, 512, 0, stream>>>(x_in, conv_w, conv_b, fc1_w, fc1_b,
                                    fc2_w, fc2_b, rot1_w, rot1_b,
                                    rot2_w, rot2_b, out);
  k_gru<<<256, 512, 0, stream>>>(gwih, gwhh, gbih, gbhh, ow, ob, out);
}